// Round 20
// baseline (250.407 us; speedup 1.0000x reference)
//
#include <hip/hip_runtime.h>

namespace {
constexpr int CH = 640, HW = 25, MS = 125;
constexpr int CHW = CH * HW;    // 16000
constexpr float GAMMA = 20.f, GAMMA2 = 10.f;
constexpr float EPS = 1e-12f;
}

// ---- prep (fast path): shot-mean + L2-norm -> sup128[b][c][128] (pad zeros) ----
__global__ __launch_bounds__(256)
void prep_sup128_kernel(const float* __restrict__ sup, float* __restrict__ supt) {
  __shared__ __align__(16) float m[CHW];
  __shared__ float inv[HW];
  const int bn = blockIdx.x;               // b*5 + n
  const int b = bn / 5, n = bn % 5;
  const float* base = sup + ((size_t)b * 25 + n * 5) * CHW;
  for (int idx = threadIdx.x; idx < CHW; idx += 256) {
    float s = 0.f;
    #pragma unroll
    for (int sh = 0; sh < 5; ++sh) s += base[sh * CHW + idx];
    m[idx] = s * 0.2f;
  }
  __syncthreads();
  {
    int i = threadIdx.x >> 3, s8 = threadIdx.x & 7;
    if (i < HW) {
      float p = 0.f;
      for (int c = s8; c < CH; c += 8) { float v = m[c * HW + i]; p += v * v; }
      p += __shfl_xor(p, 1); p += __shfl_xor(p, 2); p += __shfl_xor(p, 4);
      if (s8 == 0) inv[i] = rsqrtf(p + EPS);
    }
  }
  __syncthreads();
  float* ob = supt + (size_t)b * (CH * 128);
  for (int idx = threadIdx.x; idx < CHW; idx += 256) {
    int c = idx / 25, i = idx - c * 25;
    ob[c * 128 + n * 25 + i] = m[idx] * inv[i];
  }
  if (n == 0)
    for (int c = threadIdx.x; c < CH; c += 256) {
      ob[c * 128 + 125] = 0.f; ob[c * 128 + 126] = 0.f; ob[c * 128 + 127] = 0.f;
    }
}

// ---- prep (fallback): -> sup_t[b][nk][c] ----
__global__ __launch_bounds__(256)
void prep_sup_kernel(const float* __restrict__ sup, float* __restrict__ sup_t) {
  __shared__ __align__(16) float m[CHW];
  __shared__ float inv[HW];
  const int bn = blockIdx.x;
  const float* base = sup + (size_t)(bn / 5) * (25 * CHW) + (size_t)(bn % 5) * (5 * CHW);
  for (int idx = threadIdx.x; idx < CHW; idx += 256) {
    float s = 0.f;
    #pragma unroll
    for (int sh = 0; sh < 5; ++sh) s += base[sh * CHW + idx];
    m[idx] = s * 0.2f;
  }
  __syncthreads();
  {
    int i = threadIdx.x >> 3, s8 = threadIdx.x & 7;
    if (i < HW) {
      float p = 0.f;
      for (int c = s8; c < CH; c += 8) { float v = m[c * HW + i]; p += v * v; }
      p += __shfl_xor(p, 1); p += __shfl_xor(p, 2); p += __shfl_xor(p, 4);
      if (s8 == 0) inv[i] = rsqrtf(p + EPS);
    }
  }
  __syncthreads();
  float* outp = sup_t + (size_t)bn * CHW;
  for (int idx = threadIdx.x; idx < CHW; idx += 256) {
    int k = idx / CH, c = idx - k * CH;
    outp[idx] = m[c * HW + k] * inv[k];
  }
}

// ---- Phase 1: 125x125 S GEMM; ring-3 K8 chunks, counted vmcnt(5) (T4) ----
// Per wave per chunk: exactly 5 async global_load_lds (4x A width-4, 1x B width-16).
__global__ __launch_bounds__(256)
void gemm_s3_kernel(const float* __restrict__ qry, const float* __restrict__ sup128,
                    float* __restrict__ Sout) {
  __shared__ __align__(16) float atile[3][8 * 128];   // [slot][k][row]
  __shared__ __align__(16) float btile[3][8 * 128];   // [slot][k][col]
  __shared__ float invq_s[128];

  const int tid = threadIdx.x;
  const int wid = tid >> 6, lane = tid & 63;
  // XCD swizzle: 480 = 8*60
  const int Bl = (blockIdx.x & 7) * 60 + (blockIdx.x >> 3);
  const int b = Bl / 15, qg = Bl - 15 * b;
  const float* qbase = qry + ((size_t)b * 75 + (size_t)qg * 5) * CHW;
  const float* sb = sup128 + (size_t)b * (CH * 128);
  const int ty = tid >> 4, tx = tid & 15;

  // per-lane A-source mapping (clamped -> full exec; pad slots get dup data)
  const int row0 = lane;
  const int qq0 = row0 / 25, i0 = row0 - 25 * qq0;
  int row1 = 64 + lane; if (row1 > 124) row1 = 124;
  const int qq1 = row1 / 25, i1 = row1 - 25 * qq1;
  const size_t aoff0 = (size_t)qq0 * CHW + i0;   // + (c0+k)*25
  const size_t aoff1 = (size_t)qq1 * CHW + i1;

  // stage K8 chunk starting at channel c0 into ring slot (async, full-exec)
  auto STAGE = [&](int slot, int c0) {
    float* at = atile[slot];
    float* bt = btile[slot];
    #pragma unroll
    for (int rr = 0; rr < 4; ++rr) {              // A: 4 width-4 calls/wave
      const int r = 4 * wid + rr;                 // 0..15 (k = r>>1, half = r&1)
      const int k = r >> 1;
      const size_t aoff = (r & 1) ? aoff1 : aoff0;
      const float* src = qbase + aoff + (size_t)(c0 + k) * 25;
      __builtin_amdgcn_global_load_lds(
          (const __attribute__((address_space(1))) void*)src,
          (__attribute__((address_space(3))) void*)(at + r * 64), 4, 0, 0);
    }
    {                                             // B: 1 width-16 call/wave
      const int j = wid;                          // 0..3, covers k-rows 2j,2j+1
      const float* src = sb + (size_t)(c0 + 2 * j) * 128 + lane * 4;
      __builtin_amdgcn_global_load_lds(
          (const __attribute__((address_space(1))) void*)src,
          (__attribute__((address_space(3))) void*)(bt + j * 256), 16, 0, 0);
    }
  };

  float acc[2][2][4][4];
  #pragma unroll
  for (int g = 0; g < 2; ++g)
    #pragma unroll
    for (int h = 0; h < 2; ++h)
      #pragma unroll
      for (int u = 0; u < 4; ++u)
        #pragma unroll
        for (int v = 0; v < 4; ++v) acc[g][h][u][v] = 0.f;
  float npart = 0.f;

  // prologue: chunks 0 and 1 in flight; retire chunk 0, keep chunk 1 flying
  STAGE(0, 0);
  STAGE(1, 8);
  asm volatile("s_waitcnt vmcnt(5)" ::: "memory");
  __syncthreads();

  for (int t = 0; t < 80; ++t) {
    if (t < 78) STAGE((t + 2) % 3, 8 * (t + 2));  // depth-2 prefetch
    const float* at = atile[t % 3];
    const float* bt = btile[t % 3];
    if (tid < MS) {
      #pragma unroll
      for (int k = 0; k < 8; ++k) { float v = at[k * 128 + tid]; npart += v * v; }
    }
    #pragma unroll
    for (int k = 0; k < 8; ++k) {
      const float4 a0 = *(const float4*)&at[k * 128 + 4 * ty];
      const float4 a1 = *(const float4*)&at[k * 128 + 64 + 4 * ty];
      const float4 b0 = *(const float4*)&bt[k * 128 + 4 * tx];
      const float4 b1 = *(const float4*)&bt[k * 128 + 64 + 4 * tx];
      const float ag[2][4] = {{a0.x, a0.y, a0.z, a0.w}, {a1.x, a1.y, a1.z, a1.w}};
      const float bg[2][4] = {{b0.x, b0.y, b0.z, b0.w}, {b1.x, b1.y, b1.z, b1.w}};
      #pragma unroll
      for (int g = 0; g < 2; ++g)
        #pragma unroll
        for (int u = 0; u < 4; ++u)
          #pragma unroll
          for (int h = 0; h < 2; ++h)
            #pragma unroll
            for (int v = 0; v < 4; ++v) acc[g][h][u][v] += ag[g][u] * bg[h][v];
    }
    if (t < 78) {
      // retire chunk t+1 (oldest 5); chunk t+2's 5 stay in flight across barrier
      asm volatile("s_waitcnt vmcnt(5)" ::: "memory");
      __syncthreads();
    } else if (t == 78) {
      asm volatile("s_waitcnt vmcnt(0)" ::: "memory");  // drain chunk 79
      __syncthreads();
    }
  }
  if (tid < MS) invq_s[tid] = rsqrtf(npart + EPS);
  __syncthreads();

  float* Sg = Sout + (size_t)(b * 75 + qg * 5) * 3200;
  #pragma unroll
  for (int g = 0; g < 2; ++g)
    #pragma unroll
    for (int u = 0; u < 4; ++u) {
      const int row = g * 64 + 4 * ty + u;
      if (row < MS) {
        const float iv = invq_s[row];
        const int qq = row / 25, r = row - 25 * qq;
        #pragma unroll
        for (int h = 0; h < 2; ++h) {
          float4 val;
          val.x = acc[g][h][u][0] * iv;
          val.y = acc[g][h][u][1] * iv;
          val.z = acc[g][h][u][2] * iv;
          val.w = acc[g][h][u][3] * iv;
          *(float4*)(Sg + (size_t)qq * 3200 + r * 128 + h * 64 + 4 * tx) = val;
        }
      }
    }
}

// ---- Phase 2: per-(b,q) solve ----
__global__ __launch_bounds__(256)
void solve_kernel(const float* __restrict__ Sg, float* __restrict__ out) {
  __shared__ float Sld[25 * 131];
  __shared__ float Qm[3125];
  __shared__ double Msol[675];
  __shared__ double xsd[HW];
  __shared__ float kqs[HW];
  __shared__ float ksf[MS];

  const int tid = threadIdx.x;
  const int bq = blockIdx.x;
  const float* src = Sg + (size_t)bq * 3200;
  for (int idx = tid; idx < 3200; idx += 256) {
    const int row = idx >> 7, c = idx & 127;
    Sld[row * 131 + c] = src[idx];
  }
  __syncthreads();

  if (tid < MS) {
    float mx = -1e30f;
    #pragma unroll
    for (int i = 0; i < HW; ++i) mx = fmaxf(mx, Sld[i * 131 + tid]);
    float e[HW]; float sum = 0.f;
    #pragma unroll
    for (int i = 0; i < HW; ++i) { e[i] = __expf(GAMMA2 * (Sld[i * 131 + tid] - mx)); sum += e[i]; }
    float is = 1.f / sum;
    #pragma unroll
    for (int i = 0; i < HW; ++i) Qm[tid * HW + i] = e[i] * is;
  }
  __syncthreads();

  {
    int i = tid >> 3, s8 = tid & 7;
    if (i < HW) {
      float mx = -1e30f;
      for (int j = s8; j < MS; j += 8) mx = fmaxf(mx, Sld[i * 131 + j]);
      mx = fmaxf(mx, __shfl_xor(mx, 1));
      mx = fmaxf(mx, __shfl_xor(mx, 2));
      mx = fmaxf(mx, __shfl_xor(mx, 4));
      float sum = 0.f;
      for (int j = s8; j < MS; j += 8) {
        float e = __expf(GAMMA * (Sld[i * 131 + j] - mx));
        Sld[i * 131 + j] = e; sum += e;
      }
      sum += __shfl_xor(sum, 1); sum += __shfl_xor(sum, 2); sum += __shfl_xor(sum, 4);
      float is = 1.f / sum;
      for (int j = s8; j < MS; j += 8) Sld[i * 131 + j] *= is;
    }
  }
  __syncthreads();

  #pragma unroll
  for (int t = 0; t < 3; ++t) {
    const int pp = tid + 256 * t;
    if (pp < 650) {
      const int i = pp / 26, i2 = pp - 26 * i;
      float s = 0.f;
      if (i2 < 25) {
        for (int j = 0; j < MS; ++j) s += Qm[j * HW + i] * Sld[i2 * 131 + j];
        Msol[i * 27 + i2] = (i == i2 ? 1.0 : 0.0) - 0.998001 * (double)s;
      } else {
        for (int j = 0; j < MS; ++j) s += Qm[j * HW + i];
        Msol[i * 27 + 25] = 1.0 + 0.999 * (double)s;
      }
    }
  }
  __syncthreads();

  for (int k = 0; k < 24; ++k) {
    const double invp = 1.0 / Msol[k * 27 + k];
    const int jj = k + 1 + (tid & 31);
    for (int i = k + 1 + (tid >> 5); i < HW; i += 8) {
      const double f = Msol[i * 27 + k] * invp;
      if (jj <= HW) Msol[i * 27 + jj] -= f * Msol[k * 27 + jj];
    }
    __syncthreads();
  }
  for (int k = 24; k >= 0; --k) {
    const double xk = Msol[k * 27 + 25] / Msol[k * 27 + k];
    if (tid == 0) xsd[k] = xk;
    if (tid < k) Msol[tid * 27 + 25] -= Msol[tid * 27 + k] * xk;
    __syncthreads();
  }

  if (tid < HW) kqs[tid] = (float)(xsd[tid] - 1.0);
  if (tid < MS) {
    float a = 0.f;
    #pragma unroll
    for (int i = 0; i < HW; ++i) a += Sld[i * 131 + tid] * (float)xsd[i];
    ksf[tid] = 0.999f * a;
  }
  __syncthreads();
  if (tid < HW) {
    float s = 0.f;
    #pragma unroll
    for (int i = 0; i < HW; ++i) s += kqs[i];
    out[(size_t)bq * HW + tid] = kqs[tid] / s;
  }
  if (tid < MS) {
    const int n = tid / HW;
    float s = 0.f;
    #pragma unroll
    for (int k2 = 0; k2 < HW; ++k2) s += ksf[n * HW + k2];
    out[60000 + (size_t)bq * MS + tid] = ksf[tid] / s;
  }
}

// ---- Fallback (ws too small): r12 proven monolithic kernel ----
__global__ __launch_bounds__(256)
void melmask_kernel(const float* __restrict__ qry, const float* __restrict__ sup_t,
                    float* __restrict__ out) {
  __shared__ __align__(16) float pool[4224];
  __shared__ __align__(16) float Sld[3125];
  __shared__ double Msol[675];
  __shared__ double xsd[HW];
  __shared__ float invq_s[128];
  __shared__ float kqs[HW];
  __shared__ float ksf[MS];

  float* atile = pool;
  float* btile = pool + 2112;
  float* Qm    = pool;

  const int tid = threadIdx.x;
  const int Bl = (blockIdx.x & 7) * 60 + (blockIdx.x >> 3);
  const int b = Bl / 15, qg = Bl - 15 * b;
  const float* qbase = qry + ((size_t)b * 75 + (size_t)qg * 5) * CHW;
  const float* sbase = sup_t + (size_t)b * (MS * CH);
  const int ty = tid >> 4, tx = tid & 15;

  float acc[2][2][4][4];
  #pragma unroll
  for (int g = 0; g < 2; ++g)
    #pragma unroll
    for (int h = 0; h < 2; ++h)
      #pragma unroll
      for (int u = 0; u < 4; ++u)
        #pragma unroll
        for (int v = 0; v < 4; ++v) acc[g][h][u][v] = 0.f;
  float npart = 0.f;

  for (int c0 = 0; c0 < CH; c0 += 16) {
    __syncthreads();
    #pragma unroll
    for (int mm = 0; mm < 8; ++mm) {
      int idx = tid + 256 * mm;
      int k = idx >> 7, row = idx & 127;
      float v = 0.f;
      if (row < MS) {
        int qq = row / 25, i = row - 25 * qq;
        v = qbase[(size_t)qq * CHW + (size_t)(c0 + k) * 25 + i];
      }
      atile[k * 132 + row] = v;
    }
    #pragma unroll
    for (int mm = 0; mm < 2; ++mm) {
      int idx = tid + 256 * mm;
      int col = idx >> 2, kq = idx & 3;
      float4 v = make_float4(0.f, 0.f, 0.f, 0.f);
      if (col < MS) v = *(const float4*)(sbase + (size_t)col * CH + c0 + 4 * kq);
      btile[(4 * kq + 0) * 132 + col] = v.x;
      btile[(4 * kq + 1) * 132 + col] = v.y;
      btile[(4 * kq + 2) * 132 + col] = v.z;
      btile[(4 * kq + 3) * 132 + col] = v.w;
    }
    __syncthreads();
    if (tid < MS) {
      #pragma unroll
      for (int k = 0; k < 16; ++k) { float v = atile[k * 132 + tid]; npart += v * v; }
    }
    #pragma unroll
    for (int k = 0; k < 16; ++k) {
      const float4 a0 = *(const float4*)&atile[k * 132 + 4 * ty];
      const float4 a1 = *(const float4*)&atile[k * 132 + 64 + 4 * ty];
      const float4 b0 = *(const float4*)&btile[k * 132 + 4 * tx];
      const float4 b1 = *(const float4*)&btile[k * 132 + 64 + 4 * tx];
      const float ag[2][4] = {{a0.x, a0.y, a0.z, a0.w}, {a1.x, a1.y, a1.z, a1.w}};
      const float bg[2][4] = {{b0.x, b0.y, b0.z, b0.w}, {b1.x, b1.y, b1.z, b1.w}};
      #pragma unroll
      for (int g = 0; g < 2; ++g)
        #pragma unroll
        for (int u = 0; u < 4; ++u)
          #pragma unroll
          for (int h = 0; h < 2; ++h)
            #pragma unroll
            for (int v = 0; v < 4; ++v) acc[g][h][u][v] += ag[g][u] * bg[h][v];
    }
  }
  if (tid < MS) invq_s[tid] = rsqrtf(npart + EPS);
  __syncthreads();

  for (int qq = 0; qq < 5; ++qq) {
    const int bq = b * 75 + qg * 5 + qq;
    const int r0 = qq * 25;
    #pragma unroll
    for (int g = 0; g < 2; ++g)
      #pragma unroll
      for (int u = 0; u < 4; ++u) {
        const int row = g * 64 + 4 * ty + u;
        if (row >= r0 && row < r0 + 25) {
          const int r = row - r0;
          const float iv = invq_s[row];
          #pragma unroll
          for (int h = 0; h < 2; ++h)
            #pragma unroll
            for (int v = 0; v < 4; ++v) {
              const int col = h * 64 + 4 * tx + v;
              if (col < MS) Sld[r * MS + col] = acc[g][h][u][v] * iv;
            }
        }
      }
    __syncthreads();
    if (tid < MS) {
      float mx = -1e30f;
      #pragma unroll
      for (int i = 0; i < HW; ++i) mx = fmaxf(mx, Sld[i * MS + tid]);
      float e[HW]; float sum = 0.f;
      #pragma unroll
      for (int i = 0; i < HW; ++i) { e[i] = __expf(GAMMA2 * (Sld[i * MS + tid] - mx)); sum += e[i]; }
      float is = 1.f / sum;
      #pragma unroll
      for (int i = 0; i < HW; ++i) Qm[tid * HW + i] = e[i] * is;
    }
    __syncthreads();
    {
      int i = tid >> 3, s8 = tid & 7;
      if (i < HW) {
        float mx = -1e30f;
        for (int j = s8; j < MS; j += 8) mx = fmaxf(mx, Sld[i * MS + j]);
        mx = fmaxf(mx, __shfl_xor(mx, 1));
        mx = fmaxf(mx, __shfl_xor(mx, 2));
        mx = fmaxf(mx, __shfl_xor(mx, 4));
        float sum = 0.f;
        for (int j = s8; j < MS; j += 8) {
          float e = __expf(GAMMA * (Sld[i * MS + j] - mx));
          Sld[i * MS + j] = e; sum += e;
        }
        sum += __shfl_xor(sum, 1); sum += __shfl_xor(sum, 2); sum += __shfl_xor(sum, 4);
        float is = 1.f / sum;
        for (int j = s8; j < MS; j += 8) Sld[i * MS + j] *= is;
      }
    }
    __syncthreads();
    float* P = Sld;
    #pragma unroll
    for (int t = 0; t < 3; ++t) {
      const int pp = tid + 256 * t;
      if (pp < 650) {
        const int i = pp / 26, i2 = pp - 26 * i;
        float s = 0.f;
        if (i2 < 25) {
          for (int j = 0; j < MS; ++j) s += Qm[j * HW + i] * P[i2 * MS + j];
          Msol[i * 27 + i2] = (i == i2 ? 1.0 : 0.0) - 0.998001 * (double)s;
        } else {
          for (int j = 0; j < MS; ++j) s += Qm[j * HW + i];
          Msol[i * 27 + 25] = 1.0 + 0.999 * (double)s;
        }
      }
    }
    __syncthreads();
    for (int k = 0; k < 24; ++k) {
      const double invp = 1.0 / Msol[k * 27 + k];
      const int jj = k + 1 + (tid & 31);
      for (int i = k + 1 + (tid >> 5); i < HW; i += 8) {
        const double f = Msol[i * 27 + k] * invp;
        if (jj <= HW) Msol[i * 27 + jj] -= f * Msol[k * 27 + jj];
      }
      __syncthreads();
    }
    for (int k = 24; k >= 0; --k) {
      const double xk = Msol[k * 27 + 25] / Msol[k * 27 + k];
      if (tid == 0) xsd[k] = xk;
      if (tid < k) Msol[tid * 27 + 25] -= Msol[tid * 27 + k] * xk;
      __syncthreads();
    }
    if (tid < HW) kqs[tid] = (float)(xsd[tid] - 1.0);
    if (tid < MS) {
      float a = 0.f;
      #pragma unroll
      for (int i = 0; i < HW; ++i) a += P[i * MS + tid] * (float)xsd[i];
      ksf[tid] = 0.999f * a;
    }
    __syncthreads();
    if (tid < HW) {
      float s = 0.f;
      #pragma unroll
      for (int i = 0; i < HW; ++i) s += kqs[i];
      out[(size_t)bq * HW + tid] = kqs[tid] / s;
    }
    if (tid < MS) {
      const int n = tid / HW;
      float s = 0.f;
      #pragma unroll
      for (int k2 = 0; k2 < HW; ++k2) s += ksf[n * HW + k2];
      out[60000 + (size_t)bq * MS + tid] = ksf[tid] / s;
    }
    __syncthreads();
  }
}

extern "C" void kernel_launch(void* const* d_in, const int* in_sizes, int n_in,
                              void* d_out, int out_size, void* d_ws, size_t ws_size,
                              hipStream_t stream) {
  const float* sup = (const float*)d_in[0];
  const float* qry = (const float*)d_in[1];
  float* outp = (float*)d_out;
  const size_t sup128_bytes = (size_t)32 * CH * 128 * 4;     // 10,485,760
  const size_t sg_bytes = (size_t)2400 * 3200 * 4;           // 30,720,000
  if (ws_size >= sup128_bytes + sg_bytes) {
    float* sup128 = (float*)d_ws;
    float* Sg = (float*)((char*)d_ws + sup128_bytes);
    prep_sup128_kernel<<<160, 256, 0, stream>>>(sup, sup128);
    gemm_s3_kernel<<<480, 256, 0, stream>>>(qry, sup128, Sg);
    solve_kernel<<<2400, 256, 0, stream>>>(Sg, outp);
  } else {
    float* sup_t = (float*)d_ws;                             // 10,240,000
    prep_sup_kernel<<<160, 256, 0, stream>>>(sup, sup_t);
    melmask_kernel<<<480, 256, 0, stream>>>(qry, sup_t, outp);
  }
}

// Round 21
// 243.065 us; speedup vs baseline: 1.0302x; 1.0302x over previous
//
#include <hip/hip_runtime.h>

namespace {
constexpr int CH = 640, HW = 25, MS = 125;
constexpr int CHW = CH * HW;    // 16000
constexpr float GAMMA = 20.f, GAMMA2 = 10.f;
constexpr float EPS = 1e-12f;
}

// ---- prep (fast path): shot-mean + L2-norm -> sup128[b][c][128] (pad zeros) ----
__global__ __launch_bounds__(256)
void prep_sup128_kernel(const float* __restrict__ sup, float* __restrict__ supt) {
  __shared__ __align__(16) float m[CHW];
  __shared__ float inv[HW];
  const int bn = blockIdx.x;               // b*5 + n
  const int b = bn / 5, n = bn % 5;
  const float* base = sup + ((size_t)b * 25 + n * 5) * CHW;
  for (int idx = threadIdx.x; idx < CHW; idx += 256) {
    float s = 0.f;
    #pragma unroll
    for (int sh = 0; sh < 5; ++sh) s += base[sh * CHW + idx];
    m[idx] = s * 0.2f;
  }
  __syncthreads();
  {
    int i = threadIdx.x >> 3, s8 = threadIdx.x & 7;
    if (i < HW) {
      float p = 0.f;
      for (int c = s8; c < CH; c += 8) { float v = m[c * HW + i]; p += v * v; }
      p += __shfl_xor(p, 1); p += __shfl_xor(p, 2); p += __shfl_xor(p, 4);
      if (s8 == 0) inv[i] = rsqrtf(p + EPS);
    }
  }
  __syncthreads();
  float* ob = supt + (size_t)b * (CH * 128);
  for (int idx = threadIdx.x; idx < CHW; idx += 256) {
    int c = idx / 25, i = idx - c * 25;
    ob[c * 128 + n * 25 + i] = m[idx] * inv[i];
  }
  if (n == 0)
    for (int c = threadIdx.x; c < CH; c += 256) {
      ob[c * 128 + 125] = 0.f; ob[c * 128 + 126] = 0.f; ob[c * 128 + 127] = 0.f;
    }
}

// ---- prep (fallback): -> sup_t[b][nk][c] ----
__global__ __launch_bounds__(256)
void prep_sup_kernel(const float* __restrict__ sup, float* __restrict__ sup_t) {
  __shared__ __align__(16) float m[CHW];
  __shared__ float inv[HW];
  const int bn = blockIdx.x;
  const float* base = sup + (size_t)(bn / 5) * (25 * CHW) + (size_t)(bn % 5) * (5 * CHW);
  for (int idx = threadIdx.x; idx < CHW; idx += 256) {
    float s = 0.f;
    #pragma unroll
    for (int sh = 0; sh < 5; ++sh) s += base[sh * CHW + idx];
    m[idx] = s * 0.2f;
  }
  __syncthreads();
  {
    int i = threadIdx.x >> 3, s8 = threadIdx.x & 7;
    if (i < HW) {
      float p = 0.f;
      for (int c = s8; c < CH; c += 8) { float v = m[c * HW + i]; p += v * v; }
      p += __shfl_xor(p, 1); p += __shfl_xor(p, 2); p += __shfl_xor(p, 4);
      if (s8 == 0) inv[i] = rsqrtf(p + EPS);
    }
  }
  __syncthreads();
  float* outp = sup_t + (size_t)bn * CHW;
  for (int idx = threadIdx.x; idx < CHW; idx += 256) {
    int k = idx / CH, c = idx - k * CH;
    outp[idx] = m[c * HW + k] * inv[k];
  }
}

// ---- Phase 1: 125x125 S GEMM, global_load_lds double-buffer,
//      FULL-EXEC calls (clamped sources) + EXPLICIT vmcnt drains ----
__global__ __launch_bounds__(256)
void gemm_s_kernel(const float* __restrict__ qry, const float* __restrict__ sup128,
                   float* __restrict__ Sout) {
  __shared__ __align__(16) float atile[2][16 * 128];
  __shared__ __align__(16) float btile[2][16 * 128];
  __shared__ float invq_s[128];

  const int tid = threadIdx.x;
  const int wid = tid >> 6, lane = tid & 63;
  // XCD swizzle: 480 = 8*60
  const int Bl = (blockIdx.x & 7) * 60 + (blockIdx.x >> 3);
  const int b = Bl / 15, qg = Bl - 15 * b;
  const float* qbase = qry + ((size_t)b * 75 + (size_t)qg * 5) * CHW;
  const float* sb = sup128 + (size_t)b * (CH * 128);
  const int ty = tid >> 4, tx = tid & 15;

  // Precompute per-lane A-source (query,i) pairs for the two row-halves.
  // half 0: row = lane (0..63); half 1: row = min(64+lane, 124)  [clamp -> full exec]
  const int row0 = lane;
  const int qq0 = row0 / 25, i0 = row0 - 25 * qq0;
  int row1 = 64 + lane; if (row1 > 124) row1 = 124;
  const int qq1 = row1 / 25, i1 = row1 - 25 * qq1;
  const size_t aoff0 = (size_t)qq0 * CHW + i0;   // + (c0+k)*25
  const size_t aoff1 = (size_t)qq1 * CHW + i1;

  // stage chunk starting at channel c0 into buffer pp (async, full-exec)
  auto STAGE = [&](int pp, int c0) {
    float* at = atile[pp];
    float* bt = btile[pp];
    #pragma unroll
    for (int rr = 0; rr < 8; ++rr) {
      const int r = 8 * wid + rr;                   // 0..31
      const int k = r >> 1;
      const size_t aoff = (r & 1) ? aoff1 : aoff0;
      const float* src = qbase + aoff + (size_t)(c0 + k) * 25;
      __builtin_amdgcn_global_load_lds(
          (const __attribute__((address_space(1))) void*)src,
          (__attribute__((address_space(3))) void*)(at + r * 64), 4, 0, 0);
    }
    #pragma unroll
    for (int jj = 0; jj < 2; ++jj) {
      const int j = 2 * wid + jj;                   // 0..7
      const float* src = sb + (size_t)(c0 + 2 * j) * 128 + lane * 4;
      __builtin_amdgcn_global_load_lds(
          (const __attribute__((address_space(1))) void*)src,
          (__attribute__((address_space(3))) void*)(bt + j * 256), 16, 0, 0);
    }
  };

  float acc[2][2][4][4];
  #pragma unroll
  for (int g = 0; g < 2; ++g)
    #pragma unroll
    for (int h = 0; h < 2; ++h)
      #pragma unroll
      for (int u = 0; u < 4; ++u)
        #pragma unroll
        for (int v = 0; v < 4; ++v) acc[g][h][u][v] = 0.f;
  float npart = 0.f;

  STAGE(0, 0);
  asm volatile("s_waitcnt vmcnt(0)" ::: "memory");  // explicit drain
  __syncthreads();

  int p = 0;
  for (int t = 0; t < 40; ++t) {
    if (t < 39) STAGE(p ^ 1, 16 * (t + 1));         // async prefetch next chunk
    const float* at = atile[p];
    const float* bt = btile[p];
    if (tid < MS) {
      #pragma unroll
      for (int k = 0; k < 16; ++k) { float v = at[k * 128 + tid]; npart += v * v; }
    }
    #pragma unroll
    for (int k = 0; k < 16; ++k) {
      const float4 a0 = *(const float4*)&at[k * 128 + 4 * ty];
      const float4 a1 = *(const float4*)&at[k * 128 + 64 + 4 * ty];
      const float4 b0 = *(const float4*)&bt[k * 128 + 4 * tx];
      const float4 b1 = *(const float4*)&bt[k * 128 + 64 + 4 * tx];
      const float ag[2][4] = {{a0.x, a0.y, a0.z, a0.w}, {a1.x, a1.y, a1.z, a1.w}};
      const float bg[2][4] = {{b0.x, b0.y, b0.z, b0.w}, {b1.x, b1.y, b1.z, b1.w}};
      #pragma unroll
      for (int g = 0; g < 2; ++g)
        #pragma unroll
        for (int u = 0; u < 4; ++u)
          #pragma unroll
          for (int h = 0; h < 2; ++h)
            #pragma unroll
            for (int v = 0; v < 4; ++v) acc[g][h][u][v] += ag[g][u] * bg[h][v];
    }
    asm volatile("s_waitcnt vmcnt(0)" ::: "memory"); // prefetch landed, explicit
    __syncthreads();
    p ^= 1;
  }
  if (tid < MS) invq_s[tid] = rsqrtf(npart + EPS);
  __syncthreads();

  float* Sg = Sout + (size_t)(b * 75 + qg * 5) * 3200;
  #pragma unroll
  for (int g = 0; g < 2; ++g)
    #pragma unroll
    for (int u = 0; u < 4; ++u) {
      const int row = g * 64 + 4 * ty + u;
      if (row < MS) {
        const float iv = invq_s[row];
        const int qq = row / 25, r = row - 25 * qq;
        #pragma unroll
        for (int h = 0; h < 2; ++h) {
          float4 val;
          val.x = acc[g][h][u][0] * iv;
          val.y = acc[g][h][u][1] * iv;
          val.z = acc[g][h][u][2] * iv;
          val.w = acc[g][h][u][3] * iv;
          *(float4*)(Sg + (size_t)qq * 3200 + r * 128 + h * 64 + 4 * tx) = val;
        }
      }
    }
}

// ---- Phase 2: per-(b,q) solve ----
__global__ __launch_bounds__(256)
void solve_kernel(const float* __restrict__ Sg, float* __restrict__ out) {
  __shared__ float Sld[25 * 131];
  __shared__ float Qm[3125];
  __shared__ double Msol[675];
  __shared__ double xsd[HW];
  __shared__ float kqs[HW];
  __shared__ float ksf[MS];

  const int tid = threadIdx.x;
  const int bq = blockIdx.x;
  const float* src = Sg + (size_t)bq * 3200;
  for (int idx = tid; idx < 3200; idx += 256) {
    const int row = idx >> 7, c = idx & 127;
    Sld[row * 131 + c] = src[idx];
  }
  __syncthreads();

  if (tid < MS) {
    float mx = -1e30f;
    #pragma unroll
    for (int i = 0; i < HW; ++i) mx = fmaxf(mx, Sld[i * 131 + tid]);
    float e[HW]; float sum = 0.f;
    #pragma unroll
    for (int i = 0; i < HW; ++i) { e[i] = __expf(GAMMA2 * (Sld[i * 131 + tid] - mx)); sum += e[i]; }
    float is = 1.f / sum;
    #pragma unroll
    for (int i = 0; i < HW; ++i) Qm[tid * HW + i] = e[i] * is;
  }
  __syncthreads();

  {
    int i = tid >> 3, s8 = tid & 7;
    if (i < HW) {
      float mx = -1e30f;
      for (int j = s8; j < MS; j += 8) mx = fmaxf(mx, Sld[i * 131 + j]);
      mx = fmaxf(mx, __shfl_xor(mx, 1));
      mx = fmaxf(mx, __shfl_xor(mx, 2));
      mx = fmaxf(mx, __shfl_xor(mx, 4));
      float sum = 0.f;
      for (int j = s8; j < MS; j += 8) {
        float e = __expf(GAMMA * (Sld[i * 131 + j] - mx));
        Sld[i * 131 + j] = e; sum += e;
      }
      sum += __shfl_xor(sum, 1); sum += __shfl_xor(sum, 2); sum += __shfl_xor(sum, 4);
      float is = 1.f / sum;
      for (int j = s8; j < MS; j += 8) Sld[i * 131 + j] *= is;
    }
  }
  __syncthreads();

  #pragma unroll
  for (int t = 0; t < 3; ++t) {
    const int pp = tid + 256 * t;
    if (pp < 650) {
      const int i = pp / 26, i2 = pp - 26 * i;
      float s = 0.f;
      if (i2 < 25) {
        for (int j = 0; j < MS; ++j) s += Qm[j * HW + i] * Sld[i2 * 131 + j];
        Msol[i * 27 + i2] = (i == i2 ? 1.0 : 0.0) - 0.998001 * (double)s;
      } else {
        for (int j = 0; j < MS; ++j) s += Qm[j * HW + i];
        Msol[i * 27 + 25] = 1.0 + 0.999 * (double)s;
      }
    }
  }
  __syncthreads();

  for (int k = 0; k < 24; ++k) {
    const double invp = 1.0 / Msol[k * 27 + k];
    const int jj = k + 1 + (tid & 31);
    for (int i = k + 1 + (tid >> 5); i < HW; i += 8) {
      const double f = Msol[i * 27 + k] * invp;
      if (jj <= HW) Msol[i * 27 + jj] -= f * Msol[k * 27 + jj];
    }
    __syncthreads();
  }
  for (int k = 24; k >= 0; --k) {
    const double xk = Msol[k * 27 + 25] / Msol[k * 27 + k];
    if (tid == 0) xsd[k] = xk;
    if (tid < k) Msol[tid * 27 + 25] -= Msol[tid * 27 + k] * xk;
    __syncthreads();
  }

  if (tid < HW) kqs[tid] = (float)(xsd[tid] - 1.0);
  if (tid < MS) {
    float a = 0.f;
    #pragma unroll
    for (int i = 0; i < HW; ++i) a += Sld[i * 131 + tid] * (float)xsd[i];
    ksf[tid] = 0.999f * a;
  }
  __syncthreads();
  if (tid < HW) {
    float s = 0.f;
    #pragma unroll
    for (int i = 0; i < HW; ++i) s += kqs[i];
    out[(size_t)bq * HW + tid] = kqs[tid] / s;
  }
  if (tid < MS) {
    const int n = tid / HW;
    float s = 0.f;
    #pragma unroll
    for (int k2 = 0; k2 < HW; ++k2) s += ksf[n * HW + k2];
    out[60000 + (size_t)bq * MS + tid] = ksf[tid] / s;
  }
}

// ---- Fallback (ws too small): r12 proven monolithic kernel ----
__global__ __launch_bounds__(256)
void melmask_kernel(const float* __restrict__ qry, const float* __restrict__ sup_t,
                    float* __restrict__ out) {
  __shared__ __align__(16) float pool[4224];
  __shared__ __align__(16) float Sld[3125];
  __shared__ double Msol[675];
  __shared__ double xsd[HW];
  __shared__ float invq_s[128];
  __shared__ float kqs[HW];
  __shared__ float ksf[MS];

  float* atile = pool;
  float* btile = pool + 2112;
  float* Qm    = pool;

  const int tid = threadIdx.x;
  const int Bl = (blockIdx.x & 7) * 60 + (blockIdx.x >> 3);
  const int b = Bl / 15, qg = Bl - 15 * b;
  const float* qbase = qry + ((size_t)b * 75 + (size_t)qg * 5) * CHW;
  const float* sbase = sup_t + (size_t)b * (MS * CH);
  const int ty = tid >> 4, tx = tid & 15;

  float acc[2][2][4][4];
  #pragma unroll
  for (int g = 0; g < 2; ++g)
    #pragma unroll
    for (int h = 0; h < 2; ++h)
      #pragma unroll
      for (int u = 0; u < 4; ++u)
        #pragma unroll
        for (int v = 0; v < 4; ++v) acc[g][h][u][v] = 0.f;
  float npart = 0.f;

  for (int c0 = 0; c0 < CH; c0 += 16) {
    __syncthreads();
    #pragma unroll
    for (int mm = 0; mm < 8; ++mm) {
      int idx = tid + 256 * mm;
      int k = idx >> 7, row = idx & 127;
      float v = 0.f;
      if (row < MS) {
        int qq = row / 25, i = row - 25 * qq;
        v = qbase[(size_t)qq * CHW + (size_t)(c0 + k) * 25 + i];
      }
      atile[k * 132 + row] = v;
    }
    #pragma unroll
    for (int mm = 0; mm < 2; ++mm) {
      int idx = tid + 256 * mm;
      int col = idx >> 2, kq = idx & 3;
      float4 v = make_float4(0.f, 0.f, 0.f, 0.f);
      if (col < MS) v = *(const float4*)(sbase + (size_t)col * CH + c0 + 4 * kq);
      btile[(4 * kq + 0) * 132 + col] = v.x;
      btile[(4 * kq + 1) * 132 + col] = v.y;
      btile[(4 * kq + 2) * 132 + col] = v.z;
      btile[(4 * kq + 3) * 132 + col] = v.w;
    }
    __syncthreads();
    if (tid < MS) {
      #pragma unroll
      for (int k = 0; k < 16; ++k) { float v = atile[k * 132 + tid]; npart += v * v; }
    }
    #pragma unroll
    for (int k = 0; k < 16; ++k) {
      const float4 a0 = *(const float4*)&atile[k * 132 + 4 * ty];
      const float4 a1 = *(const float4*)&atile[k * 132 + 64 + 4 * ty];
      const float4 b0 = *(const float4*)&btile[k * 132 + 4 * tx];
      const float4 b1 = *(const float4*)&btile[k * 132 + 64 + 4 * tx];
      const float ag[2][4] = {{a0.x, a0.y, a0.z, a0.w}, {a1.x, a1.y, a1.z, a1.w}};
      const float bg[2][4] = {{b0.x, b0.y, b0.z, b0.w}, {b1.x, b1.y, b1.z, b1.w}};
      #pragma unroll
      for (int g = 0; g < 2; ++g)
        #pragma unroll
        for (int u = 0; u < 4; ++u)
          #pragma unroll
          for (int h = 0; h < 2; ++h)
            #pragma unroll
            for (int v = 0; v < 4; ++v) acc[g][h][u][v] += ag[g][u] * bg[h][v];
    }
  }
  if (tid < MS) invq_s[tid] = rsqrtf(npart + EPS);
  __syncthreads();

  for (int qq = 0; qq < 5; ++qq) {
    const int bq = b * 75 + qg * 5 + qq;
    const int r0 = qq * 25;
    #pragma unroll
    for (int g = 0; g < 2; ++g)
      #pragma unroll
      for (int u = 0; u < 4; ++u) {
        const int row = g * 64 + 4 * ty + u;
        if (row >= r0 && row < r0 + 25) {
          const int r = row - r0;
          const float iv = invq_s[row];
          #pragma unroll
          for (int h = 0; h < 2; ++h)
            #pragma unroll
            for (int v = 0; v < 4; ++v) {
              const int col = h * 64 + 4 * tx + v;
              if (col < MS) Sld[r * MS + col] = acc[g][h][u][v] * iv;
            }
        }
      }
    __syncthreads();
    if (tid < MS) {
      float mx = -1e30f;
      #pragma unroll
      for (int i = 0; i < HW; ++i) mx = fmaxf(mx, Sld[i * MS + tid]);
      float e[HW]; float sum = 0.f;
      #pragma unroll
      for (int i = 0; i < HW; ++i) { e[i] = __expf(GAMMA2 * (Sld[i * MS + tid] - mx)); sum += e[i]; }
      float is = 1.f / sum;
      #pragma unroll
      for (int i = 0; i < HW; ++i) Qm[tid * HW + i] = e[i] * is;
    }
    __syncthreads();
    {
      int i = tid >> 3, s8 = tid & 7;
      if (i < HW) {
        float mx = -1e30f;
        for (int j = s8; j < MS; j += 8) mx = fmaxf(mx, Sld[i * MS + j]);
        mx = fmaxf(mx, __shfl_xor(mx, 1));
        mx = fmaxf(mx, __shfl_xor(mx, 2));
        mx = fmaxf(mx, __shfl_xor(mx, 4));
        float sum = 0.f;
        for (int j = s8; j < MS; j += 8) {
          float e = __expf(GAMMA * (Sld[i * MS + j] - mx));
          Sld[i * MS + j] = e; sum += e;
        }
        sum += __shfl_xor(sum, 1); sum += __shfl_xor(sum, 2); sum += __shfl_xor(sum, 4);
        float is = 1.f / sum;
        for (int j = s8; j < MS; j += 8) Sld[i * MS + j] *= is;
      }
    }
    __syncthreads();
    float* P = Sld;
    #pragma unroll
    for (int t = 0; t < 3; ++t) {
      const int pp = tid + 256 * t;
      if (pp < 650) {
        const int i = pp / 26, i2 = pp - 26 * i;
        float s = 0.f;
        if (i2 < 25) {
          for (int j = 0; j < MS; ++j) s += Qm[j * HW + i] * P[i2 * MS + j];
          Msol[i * 27 + i2] = (i == i2 ? 1.0 : 0.0) - 0.998001 * (double)s;
        } else {
          for (int j = 0; j < MS; ++j) s += Qm[j * HW + i];
          Msol[i * 27 + 25] = 1.0 + 0.999 * (double)s;
        }
      }
    }
    __syncthreads();
    for (int k = 0; k < 24; ++k) {
      const double invp = 1.0 / Msol[k * 27 + k];
      const int jj = k + 1 + (tid & 31);
      for (int i = k + 1 + (tid >> 5); i < HW; i += 8) {
        const double f = Msol[i * 27 + k] * invp;
        if (jj <= HW) Msol[i * 27 + jj] -= f * Msol[k * 27 + jj];
      }
      __syncthreads();
    }
    for (int k = 24; k >= 0; --k) {
      const double xk = Msol[k * 27 + 25] / Msol[k * 27 + k];
      if (tid == 0) xsd[k] = xk;
      if (tid < k) Msol[tid * 27 + 25] -= Msol[tid * 27 + k] * xk;
      __syncthreads();
    }
    if (tid < HW) kqs[tid] = (float)(xsd[tid] - 1.0);
    if (tid < MS) {
      float a = 0.f;
      #pragma unroll
      for (int i = 0; i < HW; ++i) a += P[i * MS + tid] * (float)xsd[i];
      ksf[tid] = 0.999f * a;
    }
    __syncthreads();
    if (tid < HW) {
      float s = 0.f;
      #pragma unroll
      for (int i = 0; i < HW; ++i) s += kqs[i];
      out[(size_t)bq * HW + tid] = kqs[tid] / s;
    }
    if (tid < MS) {
      const int n = tid / HW;
      float s = 0.f;
      #pragma unroll
      for (int k2 = 0; k2 < HW; ++k2) s += ksf[n * HW + k2];
      out[60000 + (size_t)bq * MS + tid] = ksf[tid] / s;
    }
    __syncthreads();
  }
}

extern "C" void kernel_launch(void* const* d_in, const int* in_sizes, int n_in,
                              void* d_out, int out_size, void* d_ws, size_t ws_size,
                              hipStream_t stream) {
  const float* sup = (const float*)d_in[0];
  const float* qry = (const float*)d_in[1];
  float* outp = (float*)d_out;
  const size_t sup128_bytes = (size_t)32 * CH * 128 * 4;     // 10,485,760
  const size_t sg_bytes = (size_t)2400 * 3200 * 4;           // 30,720,000
  if (ws_size >= sup128_bytes + sg_bytes) {
    float* sup128 = (float*)d_ws;
    float* Sg = (float*)((char*)d_ws + sup128_bytes);
    prep_sup128_kernel<<<160, 256, 0, stream>>>(sup, sup128);
    gemm_s_kernel<<<480, 256, 0, stream>>>(qry, sup128, Sg);
    solve_kernel<<<2400, 256, 0, stream>>>(Sg, outp);
  } else {
    float* sup_t = (float*)d_ws;                             // 10,240,000
    prep_sup_kernel<<<160, 256, 0, stream>>>(sup, sup_t);
    melmask_kernel<<<480, 256, 0, stream>>>(qry, sup_t, outp);
  }
}